// Round 6
// baseline (451.486 us; speedup 1.0000x reference)
//
#include <hip/hip_runtime.h>
#include <hip/hip_fp16.h>

#define NB 2048
#define NC 8
#define NT 1024
#define EPS 1e-5f
#define SLOPE (1.0f/128.0f)
#define NELEM (2048.0f*1024.0f)
#define TB (NT*NB)

// ---- ws layout ----
// floats [0,1024)      : bn1 partials, 64 slots x 16
// floats [1024,9216)   : bn2 partials, 256 slots x 32
// floats [9216,10240)  : folded params (fp32 + packed-half2-as-uint)
// byte 65536           : xT  fp16 [T][B][8]     (32 MiB)
// byte 65536+32MiB     : pre fp16 [11][T][B]    (44 MiB planes)
#define PAR_OFF 9216
#define BN2_OFF 1024
// par-relative fp32 indices
#define PF_S4  0
#define PF_O4  8
#define PF_B1F 16
#define PF_B2F 40
#define PF_B3F 56
// packed half2 (index into (unsigned*)par)
#define PU_A4   96
#define PU_W1   128
#define PU_W2   224
#define PU_W3X  416
#define PU_W3F  460
#define PU_W3L  504
#define PU_W3FF 548
#define NPAR_DW 636
#define XT_BYTE  65536
#define PWS_BYTE (65536 + 2048*1024*8*2)

typedef _Float16 h2 __attribute__((ext_vector_type(2)));
typedef __fp16  fp16v2 __attribute__((ext_vector_type(2)));
union U32H2 { unsigned u; h2 h; fp16v2 f; unsigned short us[2]; };

__device__ __forceinline__ float leaky(float z){ return fmaxf(z, z*SLOPE); }
__device__ __forceinline__ unsigned short f2h(float v){ return __half_as_ushort(__float2half(v)); }
__device__ __forceinline__ float h2f(unsigned short u){ return __half2float(__ushort_as_half(u)); }
__device__ __forceinline__ h2 uph2(unsigned u){ U32H2 x; x.u = u; return x.h; }
__device__ __forceinline__ h2 pk(float a, float b){
    U32H2 x; x.f = __builtin_amdgcn_cvt_pkrtz(a, b); return x.h;   // v_cvt_pkrtz_f16_f32
}
// packed-f16 leaky: z*2^-7 is an exact exponent shift in fp16 -> <=1ulp vs f32 path.
__device__ __forceinline__ h2 leaky2(h2 v){
    h2 s = v * (_Float16)SLOPE;
    return __builtin_elementwise_max(v, s);
}
__device__ __forceinline__ float clamp1(float z){ return __builtin_amdgcn_fmed3f(z, -1.f, 1.f); }

#if defined(__has_builtin)
#if __has_builtin(__builtin_amdgcn_fdot2)
#define HAVE_FDOT2 1
#endif
#endif
#ifdef HAVE_FDOT2
__device__ __forceinline__ float fdot2(h2 a, h2 b, float c){ return __builtin_amdgcn_fdot2(a, b, c, false); }
#else
__device__ __forceinline__ float fdot2(h2 a, h2 b, float c){
    return c + (float)a[0]*(float)b[0] + (float)a[1]*(float)b[1];
}
#endif

// ---------------- K0: BN1 stats + transpose x -> xT[t][b][8] fp16 ----------------
__global__ __launch_bounds__(256) void k0_tr(const float* __restrict__ x,
                                             unsigned short* __restrict__ xT,
                                             float* __restrict__ ws)
{
    __shared__ unsigned short tile[64*134];
    __shared__ float sred[4][4][2];
    const int tid = threadIdx.x;
    const int bg = blockIdx.x >> 4;
    const int tg = blockIdx.x & 15;
    const int b0 = bg*16, t0 = tg*64;
    float s = 0.f, s2 = 0.f;
#pragma unroll
    for(int r=0;r<8;r++){
        const int flat4 = r*256 + tid;
        const int row = flat4 >> 4;          // 0..127 = b*8+c
        const int t4  = flat4 & 15;
        const int b = row >> 3, c = row & 7;
        float4 v = *(const float4*)(x + (size_t)(b0+b)*8192 + c*1024 + t0 + t4*4);
        s  += v.x+v.y+v.z+v.w;
        s2 += v.x*v.x+v.y*v.y+v.z*v.z+v.w*v.w;
        const int base = b*8 + c;
        tile[(t4*4+0)*134 + base] = f2h(v.x);
        tile[(t4*4+1)*134 + base] = f2h(v.y);
        tile[(t4*4+2)*134 + base] = f2h(v.z);
        tile[(t4*4+3)*134 + base] = f2h(v.w);
    }
    // per-thread c is constant within 16-lane groups
#pragma unroll
    for(int m=8;m>=1;m>>=1){ s += __shfl_xor(s,m,64); s2 += __shfl_xor(s2,m,64); }
    const int lane = tid & 63, wave = tid >> 6;
    if((lane & 15) == 0){ sred[wave][lane>>4][0] = s; sred[wave][lane>>4][1] = s2; }
    __syncthreads();
    if(tid < 16){
        const int c = tid & 7, which = tid >> 3;
        const int w0 = (c < 4) ? 0 : 1, g = c & 3;
        const float v = sred[w0][g][which] + sred[w0+2][g][which];
        atomicAdd(&ws[(blockIdx.x & 63)*16 + which*8 + c], v);
    }
#pragma unroll
    for(int r=0;r<8;r++){
        const int q = r*256 + tid;
        const int t = q >> 5, inner = q & 31;
        const unsigned int lo = *(const unsigned int*)&tile[t*134 + inner*4];
        const unsigned int hi = *(const unsigned int*)&tile[t*134 + inner*4 + 2];
        *(uint2*)(xT + ((size_t)(t0+t)*NB + b0)*8 + inner*4) = make_uint2(lo, hi);
    }
}

// ---------------- K2: finalize BN1, fold + pack all weights + zero out ----------------
__device__ __forceinline__ unsigned pk2u(float a, float b){
    U32H2 v; v.us[0] = f2h(a); v.us[1] = f2h(b); return v.u;
}
__global__ __launch_bounds__(256) void k2_fold(const float* __restrict__ g1, const float* __restrict__ bb1,
    const float* __restrict__ w1, const float* __restrict__ b1,
    const float* __restrict__ w2, const float* __restrict__ b2,
    const float* __restrict__ w3, const float* __restrict__ b3,
    const float* __restrict__ A, float* __restrict__ ws,
    float* __restrict__ out)
{
    float* par = ws + PAR_OFF;
    unsigned* paru = (unsigned*)par;
    __shared__ float st[16];
    __shared__ float sc[8], oc[8];
    const int tid = threadIdx.x;
    if(tid<16){
        float s=0.f;
        for(int i=0;i<64;i++) s += ws[i*16+tid];
        st[tid]=s;
    }
    __syncthreads();
    if(tid<8){
        const float inv = 1.0f/NELEM;
        float m  = st[tid]*inv;
        float v  = st[8+tid]*inv - m*m;
        float s_ = g1[tid]*rsqrtf(v+EPS);
        float o_ = bb1[tid] - m*s_;
        sc[tid]=s_; oc[tid]=o_;
        par[PF_S4+tid]=4.f*s_; par[PF_O4+tid]=4.f*o_;
    }
    __syncthreads();
    if(tid<24){ float a=b1[tid]; for(int c=0;c<8;c++) a += w1[tid*8+c]*oc[c]; par[PF_B1F+tid]=a; }
    if(tid<16){ par[PF_B2F+tid]=b2[tid]; }
    if(tid<11){ float a=b3[tid]; for(int c=0;c<8;c++) a += w3[tid*48+8+c]*oc[c]; par[PF_B3F+tid]=a; }
    if(tid<96){ int o=tid>>2, j=tid&3;
        paru[PU_W1+tid] = pk2u(w1[o*8+2*j]*sc[2*j], w1[o*8+2*j+1]*sc[2*j+1]); }
    if(tid<192){ int o=tid/12, j=tid-o*12;
        paru[PU_W2+tid] = pk2u(w2[o*24+2*j], w2[o*24+2*j+1]); }
    if(tid<44){ int o=tid>>2, j=tid&3; int c0=2*j, c1=2*j+1;
        float xa = w3[o*48+c0] + w3[o*48+8+c0]*sc[c0];
        float xb = w3[o*48+c1] + w3[o*48+8+c1]*sc[c1];
        paru[PU_W3X+tid] = pk2u(xa, xb);
        paru[PU_W3F+tid] = pk2u(w3[o*48+32+c0], w3[o*48+32+c1]);
        paru[PU_W3L+tid] = pk2u(w3[o*48+40+c0], w3[o*48+40+c1]);
    }
    if(tid<88){ int o=tid>>3, j=tid&7;
        paru[PU_W3FF+tid] = pk2u(w3[o*48+16+2*j], w3[o*48+16+2*j+1]); }
    if(tid<32){ int i=tid>>2, j=tid&3;
        paru[PU_A4+tid] = pk2u(4.f*A[i*8+2*j], 4.f*A[i*8+2*j+1]); }
    // zero out[] (k6 accumulates atomically); stream order precedes k6
    for(int i=tid;i<2048*11;i+=256) out[i] = 0.f;
}

// ---------------- K34: fused reservoir + FF + pre + BN2 partials ----------------
// grid: 8 bgroups(256 b) x 128 tgroups(8 t) = 1024 blocks, 4 waves/SIMD.
// KEY CHANGE vs round 3 (80.6us): all 636 folded-param dwords are staged into LDS
// once per block (one float4 per thread) and every weight read is a ds_read --
// same-address broadcast (conflict-free), adjacent dwords merge to ds_read_b128.
// Rounds 1/3/4/5 showed duration ~ tracks VMEM weight-load count (~15cyc effective
// per uniform global_load_dword, 540 dwords refetched per t-pair since they exceed
// the VGPR file): the loop was a VMEM-latency treadmill. LDS kills that path; the
// loop-invariant A-matrix (32dw) can now be register-hoisted by the compiler.
__global__ __launch_bounds__(256,4) void k34(
    const unsigned short* __restrict__ xT,
    const float* __restrict__ par_g,
    float* __restrict__ bn2,
    unsigned short* __restrict__ pws)
{
    __shared__ float spar[NPAR_DW + 4];
    const int tid = threadIdx.x;
    if(tid < NPAR_DW/4){
        ((float4*)spar)[tid] = ((const float4*)par_g)[tid];
    }
    __syncthreads();
    const float* par = spar;
    const unsigned* pu = (const unsigned*)spar;

    const int b  = (blockIdx.x >> 7)*256 + tid;
    const int tg = blockIdx.x & 127;
    const int t0 = tg*8;
    const int tw = (t0 >= 16) ? (t0 - 16) : 0;

    h2 fh[4];
#pragma unroll
    for(int j=0;j<4;j++) fh[j] = pk(0.f, 0.f);
    float s1[11], s2[11];
#pragma unroll
    for(int o=0;o<11;o++){ s1[o]=0.f; s2[o]=0.f; }

    // ---- warm-up: reservoir only ----
    for(int t=tw; t<t0; t++){
        union { float4 v; unsigned u[4]; unsigned short us[8]; } ux;
        ux.v = *(const float4*)(xT + ((size_t)t*NB + b)*8);
        float nf[8];
#pragma unroll
        for(int i=0;i<8;i++){
            float acc = fmaf(par[PF_S4+i], h2f(ux.us[i]), par[PF_O4+i]);
#pragma unroll
            for(int j=0;j<4;j++) acc = fdot2(uph2(pu[PU_A4+i*4+j]), fh[j], acc);
            nf[i] = clamp1(acc);
        }
#pragma unroll
        for(int j=0;j<4;j++) fh[j] = pk(nf[2*j], nf[2*j+1]);
    }

    // ---- main: 4 pairs of useful t ----
    for(int tp=0; tp<4; tp++){
        const int t = t0 + tp*2;
        h2 xh2[2][4], fh2[2][4];
#pragma unroll
        for(int u=0;u<2;u++){
            union { float4 v; unsigned uu[4]; unsigned short us[8]; } ux;
            ux.v = *(const float4*)(xT + ((size_t)(t+u)*NB + b)*8);
#pragma unroll
            for(int j=0;j<4;j++) xh2[u][j] = uph2(ux.uu[j]);
            float nf[8];
#pragma unroll
            for(int i=0;i<8;i++){
                float acc = fmaf(par[PF_S4+i], h2f(ux.us[i]), par[PF_O4+i]);
#pragma unroll
                for(int j=0;j<4;j++) acc = fdot2(uph2(pu[PU_A4+i*4+j]), fh[j], acc);
                nf[i] = clamp1(acc);
            }
#pragma unroll
            for(int j=0;j<4;j++){ fh[j] = pk(nf[2*j], nf[2*j+1]); fh2[u][j] = fh[j]; }
        }
        // W1: 24 out x K=8, both t
        h2 hh2[2][12];
#pragma unroll
        for(int p=0;p<12;p++){
            float za0 = par[PF_B1F+2*p], zb0 = par[PF_B1F+2*p+1];
            float za1 = za0, zb1 = zb0;
#pragma unroll
            for(int j=0;j<4;j++){
                h2 wa = uph2(pu[PU_W1+(2*p)*4+j]);
                h2 wb = uph2(pu[PU_W1+(2*p+1)*4+j]);
                za0 = fdot2(wa, xh2[0][j], za0);
                za1 = fdot2(wa, xh2[1][j], za1);
                zb0 = fdot2(wb, xh2[0][j], zb0);
                zb1 = fdot2(wb, xh2[1][j], zb1);
            }
            hh2[0][p] = leaky2(pk(za0, zb0));
            hh2[1][p] = leaky2(pk(za1, zb1));
        }
        // W2: 16 out x K=24, both t
        h2 ff2[2][8];
#pragma unroll
        for(int p=0;p<8;p++){
            float za0 = par[PF_B2F+2*p], zb0 = par[PF_B2F+2*p+1];
            float za1 = za0, zb1 = zb0;
#pragma unroll
            for(int j=0;j<12;j++){
                h2 wa = uph2(pu[PU_W2+(2*p)*12+j]);
                h2 wb = uph2(pu[PU_W2+(2*p+1)*12+j]);
                za0 = fdot2(wa, hh2[0][j], za0);
                za1 = fdot2(wa, hh2[1][j], za1);
                zb0 = fdot2(wb, hh2[0][j], zb0);
                zb1 = fdot2(wb, hh2[1][j], zb1);
            }
            ff2[0][p] = leaky2(pk(za0, zb0));
            ff2[1][p] = leaky2(pk(za1, zb1));
        }
        // lfh from packed state (exact: *2^-7 is exponent shift)
        h2 lf2[2][4];
#pragma unroll
        for(int u=0;u<2;u++)
#pragma unroll
            for(int j=0;j<4;j++) lf2[u][j] = leaky2(fh2[u][j]);
        // W3: 11 out x K=40, both t; stores + BN2 accum
        const size_t base = (size_t)t*NB + b;
#pragma unroll
        for(int o=0;o<11;o++){
            float z0 = par[PF_B3F+o], z1 = z0;
#pragma unroll
            for(int j=0;j<4;j++){
                h2 w = uph2(pu[PU_W3X+o*4+j]);
                z0 = fdot2(w, xh2[0][j], z0); z1 = fdot2(w, xh2[1][j], z1);
            }
#pragma unroll
            for(int j=0;j<4;j++){
                h2 w = uph2(pu[PU_W3F+o*4+j]);
                z0 = fdot2(w, fh2[0][j], z0); z1 = fdot2(w, fh2[1][j], z1);
            }
#pragma unroll
            for(int j=0;j<4;j++){
                h2 w = uph2(pu[PU_W3L+o*4+j]);
                z0 = fdot2(w, lf2[0][j], z0); z1 = fdot2(w, lf2[1][j], z1);
            }
#pragma unroll
            for(int j=0;j<8;j++){
                h2 w = uph2(pu[PU_W3FF+o*8+j]);
                z0 = fdot2(w, ff2[0][j], z0); z1 = fdot2(w, ff2[1][j], z1);
            }
            s1[o] += z0 + z1;
            s2[o] = fmaf(z0, z0, s2[o]);
            s2[o] = fmaf(z1, z1, s2[o]);
            pws[(size_t)o*TB + base]      = f2h(z0);   // 128B/wave coalesced
            pws[(size_t)o*TB + base + NB] = f2h(z1);
        }
    }
    // BN2 partial reduction
#pragma unroll
    for(int o=0;o<11;o++){
#pragma unroll
        for(int m=32;m>=1;m>>=1){ s1[o]+=__shfl_xor(s1[o],m,64); s2[o]+=__shfl_xor(s2[o],m,64); }
    }
    __shared__ float red[4][22];
    const int wave=tid>>6, lane=tid&63;
    if(lane==0){
#pragma unroll
        for(int o=0;o<11;o++){ red[wave][o]=s1[o]; red[wave][11+o]=s2[o]; }
    }
    __syncthreads();
    if(tid<22){
        float tot = red[0][tid]+red[1][tid]+red[2][tid]+red[3][tid];
        atomicAdd(&bn2[(blockIdx.x & 255)*32 + tid], tot);
    }
}

// ---------------- K6: fused BN2 finalize + apply + leaky + t-mean ----------------
// grid: 11 o x 2 bg x 16 tg = 352 blocks. uint2 loads: 4 b's/thread.
__global__ __launch_bounds__(256) void k6(const float* __restrict__ g2, const float* __restrict__ bb2,
                                          const float* __restrict__ ws,
                                          const unsigned short* __restrict__ pws,
                                          float* __restrict__ out)
{
    const int o  = blockIdx.x >> 5;
    const int r  = blockIdx.x & 31;
    const int bg = r & 1, tg = r >> 1;
    const int tid = threadIdx.x;

    // fused BN2 finalize: al/be for this o
    __shared__ float red[4][2];
    __shared__ float sal, sbe;
    {
        float p1 = ws[BN2_OFF + tid*32 + o];
        float p2 = ws[BN2_OFF + tid*32 + 11 + o];
#pragma unroll
        for(int m=32;m>=1;m>>=1){ p1 += __shfl_xor(p1,m,64); p2 += __shfl_xor(p2,m,64); }
        const int wave = tid>>6, lane = tid&63;
        if(lane==0){ red[wave][0]=p1; red[wave][1]=p2; }
        __syncthreads();
        if(tid==0){
            float t1 = red[0][0]+red[1][0]+red[2][0]+red[3][0];
            float t2 = red[0][1]+red[1][1]+red[2][1]+red[3][1];
            const float inv = 1.0f/NELEM;
            float m = t1*inv;
            float v = t2*inv - m*m;
            float a = g2[o]*rsqrtf(v+EPS);
            sal = a; sbe = bb2[o] - m*a;
        }
        __syncthreads();
    }
    const float al = sal, be = sbe;

    const int b0 = bg*1024 + tid*4;
    const unsigned short* pp = pws + (size_t)o*TB + b0;
    float acc0=0.f, acc1=0.f, acc2=0.f, acc3=0.f;
#pragma unroll 8
    for(int i=0;i<64;i++){
        const int t = tg*64 + i;
        uint2 u = *(const uint2*)(pp + (size_t)t*NB);
        unsigned short a0 = (unsigned short)(u.x & 0xffff), a1 = (unsigned short)(u.x >> 16);
        unsigned short c0 = (unsigned short)(u.y & 0xffff), c1 = (unsigned short)(u.y >> 16);
        acc0 += leaky(fmaf(al, h2f(a0), be));
        acc1 += leaky(fmaf(al, h2f(a1), be));
        acc2 += leaky(fmaf(al, h2f(c0), be));
        acc3 += leaky(fmaf(al, h2f(c1), be));
    }
    atomicAdd(&out[(b0+0)*11+o], acc0*(1.0f/NT));
    atomicAdd(&out[(b0+1)*11+o], acc1*(1.0f/NT));
    atomicAdd(&out[(b0+2)*11+o], acc2*(1.0f/NT));
    atomicAdd(&out[(b0+3)*11+o], acc3*(1.0f/NT));
}

extern "C" void kernel_launch(void* const* d_in, const int* in_sizes, int n_in,
                              void* d_out, int out_size, void* d_ws, size_t ws_size,
                              hipStream_t stream)
{
    const float* x   = (const float*)d_in[0];
    const float* A   = (const float*)d_in[1];
    const float* g1  = (const float*)d_in[2];
    const float* bb1 = (const float*)d_in[3];
    const float* w1  = (const float*)d_in[4];
    const float* b1  = (const float*)d_in[5];
    const float* w2  = (const float*)d_in[6];
    const float* b2  = (const float*)d_in[7];
    const float* w3  = (const float*)d_in[8];
    const float* b3  = (const float*)d_in[9];
    const float* g2  = (const float*)d_in[10];
    const float* bb2 = (const float*)d_in[11];
    float* out = (float*)d_out;
    float* ws  = (float*)d_ws;
    unsigned short* xT  = (unsigned short*)((char*)d_ws + XT_BYTE);
    unsigned short* pws = (unsigned short*)((char*)d_ws + PWS_BYTE);

    (void)hipMemsetAsync(d_ws, 0, 40960, stream);                 // bn1/bn2 slots
    k0_tr  <<<2048, 256, 0, stream>>>(x, xT, ws);
    k2_fold<<<1,    256, 0, stream>>>(g1, bb1, w1, b1, w2, b2, w3, b3, A, ws, out);
    k34    <<<1024, 256, 0, stream>>>(xT, ws + PAR_OFF, ws + BN2_OFF, pws);
    k6     <<<352,  256, 0, stream>>>(g2, bb2, ws, pws, out);
}

// Round 7
// 201.786 us; speedup vs baseline: 2.2374x; 2.2374x over previous
//
#include <hip/hip_runtime.h>
#include <hip/hip_fp16.h>

#define NB 2048
#define NC 8
#define NT 1024
#define EPS 1e-5f
#define SLOPE (1.0f/128.0f)
#define NELEM (2048.0f*1024.0f)
#define TB (NT*NB)

// ---- ws layout ----
// floats [0,1024)      : bn1 partials, 64 slots x 16
// floats [1024,9216)   : bn2 partials, 256 slots x 32
// floats [9216,10240)  : reservoir params (S4/O4 f32, A4 packed h2)
// floats [10240,11584) : MFMA fragment tables (bias[64] f32 + 5 x 64 x uint4 B-frags)
// byte 65536           : xT  fp16 [T][B][8]     (32 MiB)
// byte 65536+32MiB     : pre fp16 [11][T][B]    (44 MiB planes)
#define PAR_OFF 9216
#define BN2_OFF 1024
#define P2_OFF  10240
// par-relative fp32 indices
#define PF_S4  0
#define PF_O4  8
#define PF_B1F 16
#define PF_B2F 40
#define PF_B3F 56
// packed half2 (index into (unsigned*)par)
#define PU_A4   96
#define XT_BYTE  65536
#define PWS_BYTE (65536 + 2048*1024*8*2)

// LDS row-buffer geometry (halves). 40h = 80B rows -> 16B-aligned frag reads.
#define ROWH 40
#define ZH   18

typedef _Float16 h2 __attribute__((ext_vector_type(2)));
typedef _Float16 half8 __attribute__((ext_vector_type(8)));
typedef float f32x4 __attribute__((ext_vector_type(4)));
typedef __fp16  fp16v2 __attribute__((ext_vector_type(2)));
union U32H2 { unsigned u; h2 h; fp16v2 f; unsigned short us[2]; };
union UF { uint4 u; half8 h; };

__device__ __forceinline__ float leaky(float z){ return fmaxf(z, z*SLOPE); }
__device__ __forceinline__ unsigned short f2h(float v){ return __half_as_ushort(__float2half(v)); }
__device__ __forceinline__ float h2f(unsigned short u){ return __half2float(__ushort_as_half(u)); }
__device__ __forceinline__ h2 uph2(unsigned u){ U32H2 x; x.u = u; return x.h; }
__device__ __forceinline__ h2 pk(float a, float b){
    U32H2 x; x.f = __builtin_amdgcn_cvt_pkrtz(a, b); return x.h;   // v_cvt_pkrtz_f16_f32
}
// packed-f16 leaky: z*2^-7 is an exact exponent shift in fp16.
__device__ __forceinline__ h2 leaky2(h2 v){
    h2 s = v * (_Float16)SLOPE;
    return __builtin_elementwise_max(v, s);
}
__device__ __forceinline__ float clamp1(float z){ return __builtin_amdgcn_fmed3f(z, -1.f, 1.f); }

#if defined(__has_builtin)
#if __has_builtin(__builtin_amdgcn_fdot2)
#define HAVE_FDOT2 1
#endif
#endif
#ifdef HAVE_FDOT2
__device__ __forceinline__ float fdot2(h2 a, h2 b, float c){ return __builtin_amdgcn_fdot2(a, b, c, false); }
#else
__device__ __forceinline__ float fdot2(h2 a, h2 b, float c){
    return c + (float)a[0]*(float)b[0] + (float)a[1]*(float)b[1];
}
#endif

// ---------------- K0: BN1 stats + transpose x -> xT[t][b][8] fp16 ----------------
__global__ __launch_bounds__(256) void k0_tr(const float* __restrict__ x,
                                             unsigned short* __restrict__ xT,
                                             float* __restrict__ ws)
{
    __shared__ unsigned short tile[64*134];
    __shared__ float sred[4][4][2];
    const int tid = threadIdx.x;
    const int bg = blockIdx.x >> 4;
    const int tg = blockIdx.x & 15;
    const int b0 = bg*16, t0 = tg*64;
    float s = 0.f, s2 = 0.f;
#pragma unroll
    for(int r=0;r<8;r++){
        const int flat4 = r*256 + tid;
        const int row = flat4 >> 4;          // 0..127 = b*8+c
        const int t4  = flat4 & 15;
        const int b = row >> 3, c = row & 7;
        float4 v = *(const float4*)(x + (size_t)(b0+b)*8192 + c*1024 + t0 + t4*4);
        s  += v.x+v.y+v.z+v.w;
        s2 += v.x*v.x+v.y*v.y+v.z*v.z+v.w*v.w;
        const int base = b*8 + c;
        tile[(t4*4+0)*134 + base] = f2h(v.x);
        tile[(t4*4+1)*134 + base] = f2h(v.y);
        tile[(t4*4+2)*134 + base] = f2h(v.z);
        tile[(t4*4+3)*134 + base] = f2h(v.w);
    }
#pragma unroll
    for(int m=8;m>=1;m>>=1){ s += __shfl_xor(s,m,64); s2 += __shfl_xor(s2,m,64); }
    const int lane = tid & 63, wave = tid >> 6;
    if((lane & 15) == 0){ sred[wave][lane>>4][0] = s; sred[wave][lane>>4][1] = s2; }
    __syncthreads();
    if(tid < 16){
        const int c = tid & 7, which = tid >> 3;
        const int w0 = (c < 4) ? 0 : 1, g = c & 3;
        const float v = sred[w0][g][which] + sred[w0+2][g][which];
        atomicAdd(&ws[(blockIdx.x & 63)*16 + which*8 + c], v);
    }
#pragma unroll
    for(int r=0;r<8;r++){
        const int q = r*256 + tid;
        const int t = q >> 5, inner = q & 31;
        const unsigned int lo = *(const unsigned int*)&tile[t*134 + inner*4];
        const unsigned int hi = *(const unsigned int*)&tile[t*134 + inner*4 + 2];
        *(uint2*)(xT + ((size_t)(t0+t)*NB + b0)*8 + inner*4) = make_uint2(lo, hi);
    }
}

// ---------------- K2: finalize BN1, build reservoir params + MFMA frag tables ----------------
__device__ __forceinline__ unsigned pk2u(float a, float b){
    U32H2 v; v.us[0] = f2h(a); v.us[1] = f2h(b); return v.u;
}
__global__ __launch_bounds__(256) void k2_fold(const float* __restrict__ g1, const float* __restrict__ bb1,
    const float* __restrict__ w1, const float* __restrict__ b1,
    const float* __restrict__ w2, const float* __restrict__ b2,
    const float* __restrict__ w3, const float* __restrict__ b3,
    const float* __restrict__ A, float* __restrict__ ws,
    float* __restrict__ out)
{
    float* par = ws + PAR_OFF;
    unsigned* paru = (unsigned*)par;
    __shared__ float st[16];
    __shared__ float ssc[8], soc[8], sb1f[24], sb3f[11];
    const int tid = threadIdx.x;
    if(tid<16){
        float s=0.f;
        for(int i=0;i<64;i++) s += ws[i*16+tid];
        st[tid]=s;
    }
    __syncthreads();
    if(tid<8){
        const float inv = 1.0f/NELEM;
        float m  = st[tid]*inv;
        float v  = st[8+tid]*inv - m*m;
        float s_ = g1[tid]*rsqrtf(v+EPS);
        float o_ = bb1[tid] - m*s_;
        ssc[tid]=s_; soc[tid]=o_;
        par[PF_S4+tid]=4.f*s_; par[PF_O4+tid]=4.f*o_;
    }
    __syncthreads();
    if(tid<24){ float a=b1[tid]; for(int c=0;c<8;c++) a += w1[tid*8+c]*soc[c]; sb1f[tid]=a; par[PF_B1F+tid]=a; }
    if(tid<16){ par[PF_B2F+tid]=b2[tid]; }
    if(tid<11){ float a=b3[tid]; for(int c=0;c<8;c++) a += w3[tid*48+8+c]*soc[c]; sb3f[tid]=a; par[PF_B3F+tid]=a; }
    if(tid<32){ int i=tid>>2, j=tid&3;
        paru[PU_A4+tid] = pk2u(4.f*A[i*8+2*j], 4.f*A[i*8+2*j+1]); }
    __syncthreads();

    // ---- MFMA fragment tables ----
    // B-frag layout for v_mfma_f32_16x16x32_f16: lane l holds col n=l&15, k=(l>>4)*8+j (j=0..7).
    // w3 row layout: [x 0..7][bw 8..15][ff 16..31][f 32..39][lf 40..47]
    unsigned* pt = (unsigned*)(ws + P2_OFF);
    if(tid<64){
        const int n = tid & 15, kq = tid >> 4;
        float v[8];
        // TW1A: o=n, B[k][o] = k<8 ? w1[o][k]*sc[k] : 0
#pragma unroll
        for(int j=0;j<8;j++){ int k=kq*8+j; v[j] = (k<8)? w1[n*8+k]*ssc[k] : 0.f; }
        for(int j=0;j<4;j++) pt[64 + 0*256 + tid*4 + j] = pk2u(v[2*j], v[2*j+1]);
        // TW1B: o=16+n (valid o<24)
#pragma unroll
        for(int j=0;j<8;j++){ int k=kq*8+j; int o=16+n;
            v[j] = (o<24 && k<8)? w1[o*8+k]*ssc[k] : 0.f; }
        for(int j=0;j<4;j++) pt[64 + 1*256 + tid*4 + j] = pk2u(v[2*j], v[2*j+1]);
        // TW2: o=n, k<24 -> w2[o][k]
#pragma unroll
        for(int j=0;j<8;j++){ int k=kq*8+j; v[j] = (k<24)? w2[n*24+k] : 0.f; }
        for(int j=0;j<4;j++) pt[64 + 2*256 + tid*4 + j] = pk2u(v[2*j], v[2*j+1]);
        // TW3A: o=n<11; k0..7: w3x(folded bw), k8..15: f-part, k16..23: lf-part, else 0
#pragma unroll
        for(int j=0;j<8;j++){ int k=kq*8+j;
            float t = 0.f;
            if(n<11){
                if(k<8)       t = w3[n*48+k] + w3[n*48+8+k]*ssc[k];
                else if(k<16) t = w3[n*48+32+(k-8)];
                else if(k<24) t = w3[n*48+40+(k-16)];
            }
            v[j] = t; }
        for(int j=0;j<4;j++) pt[64 + 3*256 + tid*4 + j] = pk2u(v[2*j], v[2*j+1]);
        // TW3B: o=n<11; k<16 -> w3ff[o][k]
#pragma unroll
        for(int j=0;j<8;j++){ int k=kq*8+j;
            v[j] = (n<11 && k<16)? w3[n*48+16+k] : 0.f; }
        for(int j=0;j<4;j++) pt[64 + 4*256 + tid*4 + j] = pk2u(v[2*j], v[2*j+1]);
    }
    if(tid<16){
        float* bf = ws + P2_OFF;
        bf[tid]      = sb1f[tid];                       // bias W1 tile a (o=n)
        bf[16+tid]   = (tid<8)? sb1f[16+tid] : 0.f;     // bias W1 tile b (o=16+n)
        bf[32+tid]   = b2[tid];                         // bias W2
        bf[48+tid]   = (tid<11)? sb3f[tid] : 0.f;       // bias W3
    }
    // zero out[] (k6 accumulates atomically)
    for(int i=tid;i<2048*11;i+=256) out[i] = 0.f;
}

// ---------------- K34: reservoir (VALU fdot2, r3-verbatim) + MFMA FF/W3 ----------------
// grid: 8 bgroups(256 b) x 128 tgroups(8 t) = 1024 blocks, 4 waves/SIMD exact.
// Per wave per t: threads write row [x|f|lf|0] (40h stride) into wave-private LDS;
// 4 row-tiles x {A-read(b128), mfma W1a/W1b/W3a, h->LDS}, then W2, then W3b.
// s1/s2 accumulate per-lane from the f32 accumulator (C/D: col=lane&15=o,
// row=(lane>>4)*4+reg = batch, per m89-verified layout); z bounces through a
// small LDS buffer to restore b-coalesced pws stores. No __syncthreads in t-loop.
__global__ __launch_bounds__(256,4) void k34(
    const unsigned short* __restrict__ xT,
    float* __restrict__ ws,
    unsigned short* __restrict__ pws)
{
    const float* par = ws + PAR_OFF;
    const unsigned* pu = (const unsigned*)par;
    const int tid = threadIdx.x;
    const int wave = tid>>6, lane = tid&63;
    const int ln = lane&15, kb = lane>>4;
    const int b  = (blockIdx.x >> 7)*256 + tid;
    const int tg = blockIdx.x & 127;
    const int t0 = tg*8;
    const int tw = (t0 >= 16) ? (t0 - 16) : 0;

    __shared__ unsigned short lds[4*64*ROWH + 4*64*ZH];
    unsigned short* rowb = lds + wave*(64*ROWH);
    unsigned short* zbuf = lds + 4*(64*ROWH) + wave*(64*ZH);

    // hoist per-lane B-fragments + per-col biases (one-time VMEM)
    const float* p2 = ws + P2_OFF;
    const uint4* ft = (const uint4*)(p2 + 64);
    UF w1a, w1b, w2f, w3a, w3b;
    w1a.u = ft[lane];      w1b.u = ft[64+lane];  w2f.u = ft[128+lane];
    w3a.u = ft[192+lane];  w3b.u = ft[256+lane];
    const float bi1a = p2[ln], bi1b = p2[16+ln], bi2 = p2[32+ln], bi3 = p2[48+ln];

    h2 fh[4];
#pragma unroll
    for(int j=0;j<4;j++) fh[j] = pk(0.f, 0.f);
    float s1 = 0.f, s2 = 0.f;

    // ---- warm-up: reservoir only (r3-verbatim numerics) ----
    for(int t=tw; t<t0; t++){
        union { float4 v; unsigned u[4]; unsigned short us[8]; } ux;
        ux.v = *(const float4*)(xT + ((size_t)t*NB + b)*8);
        float nf[8];
#pragma unroll
        for(int i=0;i<8;i++){
            float acc = fmaf(par[PF_S4+i], h2f(ux.us[i]), par[PF_O4+i]);
#pragma unroll
            for(int j=0;j<4;j++) acc = fdot2(uph2(pu[PU_A4+i*4+j]), fh[j], acc);
            nf[i] = clamp1(acc);
        }
#pragma unroll
        for(int j=0;j<4;j++) fh[j] = pk(nf[2*j], nf[2*j+1]);
    }

    // ---- main: 8 useful t ----
    for(int t=t0; t<t0+8; ++t){
        union { float4 v; unsigned u[4]; unsigned short us[8]; } ux;
        ux.v = *(const float4*)(xT + ((size_t)t*NB + b)*8);
        float nf[8];
#pragma unroll
        for(int i=0;i<8;i++){
            float acc = fmaf(par[PF_S4+i], h2f(ux.us[i]), par[PF_O4+i]);
#pragma unroll
            for(int j=0;j<4;j++) acc = fdot2(uph2(pu[PU_A4+i*4+j]), fh[j], acc);
            nf[i] = clamp1(acc);
        }
#pragma unroll
        for(int j=0;j<4;j++) fh[j] = pk(nf[2*j], nf[2*j+1]);
        h2 lfh[4];
#pragma unroll
        for(int j=0;j<4;j++) lfh[j] = leaky2(fh[j]);

        // write my row: [x(8) | f(8) | lf(8) | zeros(8) | pad]
        {
            unsigned short* my = rowb + lane*ROWH;
            U32H2 f0,f1,f2,f3, l0,l1,l2,l3;
            f0.h=fh[0]; f1.h=fh[1]; f2.h=fh[2]; f3.h=fh[3];
            l0.h=lfh[0]; l1.h=lfh[1]; l2.h=lfh[2]; l3.h=lfh[3];
            *(uint4*)(my)      = make_uint4(ux.u[0], ux.u[1], ux.u[2], ux.u[3]);
            *(uint4*)(my + 8)  = make_uint4(f0.u, f1.u, f2.u, f3.u);
            *(uint4*)(my + 16) = make_uint4(l0.u, l1.u, l2.u, l3.u);
            *(uint4*)(my + 24) = make_uint4(0u, 0u, 0u, 0u);   // keep MFMA K-tail finite
        }

        // phase 1: W1a, W1b, W3-part1 from [x|f|lf]; write h (cols 0..31)
        f32x4 accz[4];
#pragma unroll
        for(int T=0;T<4;T++){
            half8 A1 = *(const half8*)(rowb + (T*16+ln)*ROWH + kb*8);
            f32x4 ha = {bi1a, bi1a, bi1a, bi1a};
            f32x4 hb = {bi1b, bi1b, bi1b, bi1b};
            f32x4 zz = {bi3,  bi3,  bi3,  bi3};
            ha = __builtin_amdgcn_mfma_f32_16x16x32_f16(A1, w1a.h, ha, 0,0,0);
            hb = __builtin_amdgcn_mfma_f32_16x16x32_f16(A1, w1b.h, hb, 0,0,0);
            zz = __builtin_amdgcn_mfma_f32_16x16x32_f16(A1, w3a.h, zz, 0,0,0);
            accz[T] = zz;
            unsigned short* hw = rowb + (T*16 + kb*4)*ROWH + ln;
#pragma unroll
            for(int r=0;r<4;r++){
                hw[r*ROWH]      = f2h(leaky(ha[r]));     // h cols 0..15
                hw[r*ROWH + 16] = f2h(leaky(hb[r]));     // h cols 16..31 (>=24 are exact 0)
            }
        }
        // phase 2: W2 from h; write ff (cols 0..15)
#pragma unroll
        for(int T=0;T<4;T++){
            half8 A2 = *(const half8*)(rowb + (T*16+ln)*ROWH + kb*8);
            f32x4 ff = {bi2, bi2, bi2, bi2};
            ff = __builtin_amdgcn_mfma_f32_16x16x32_f16(A2, w2f.h, ff, 0,0,0);
            unsigned short* fw = rowb + (T*16 + kb*4)*ROWH + ln;
#pragma unroll
            for(int r=0;r<4;r++) fw[r*ROWH] = f2h(leaky(ff[r]));
        }
        // phase 3: W3-part2 from ff; z post (s1/s2 + z->zbuf)
#pragma unroll
        for(int T=0;T<4;T++){
            half8 A3 = *(const half8*)(rowb + (T*16+ln)*ROWH + kb*8);
            f32x4 zz = __builtin_amdgcn_mfma_f32_16x16x32_f16(A3, w3b.h, accz[T], 0,0,0);
            unsigned short* zw = zbuf + (T*16 + kb*4)*ZH + ln;
#pragma unroll
            for(int r=0;r<4;r++){
                float z = zz[r];
                s1 += z; s2 = fmaf(z, z, s2);
                zw[r*ZH] = f2h(z);
            }
        }
        // phase 4: b-coalesced pws stores (thread = its b row)
        {
            const size_t base = (size_t)t*NB + b;
            const unsigned short* mz = zbuf + lane*ZH;
            unsigned short zv[11];
#pragma unroll
            for(int o=0;o<11;o++) zv[o] = mz[o];
#pragma unroll
            for(int o=0;o<11;o++) pws[(size_t)o*TB + base] = zv[o];
        }
    }

    // BN2 reduction: lane holds plane o=ln partials; sum the 4 kb-groups
    s1 += __shfl_xor(s1, 16, 64); s1 += __shfl_xor(s1, 32, 64);
    s2 += __shfl_xor(s2, 16, 64); s2 += __shfl_xor(s2, 32, 64);
    __shared__ float red[4][22];
    if(kb==0 && ln<11){ red[wave][ln] = s1; red[wave][11+ln] = s2; }
    __syncthreads();
    if(tid<22){
        float tot = red[0][tid]+red[1][tid]+red[2][tid]+red[3][tid];
        atomicAdd(&ws[BN2_OFF + (blockIdx.x & 255)*32 + tid], tot);
    }
}

// ---------------- K6: fused BN2 finalize + apply + leaky + t-mean ----------------
__global__ __launch_bounds__(256) void k6(const float* __restrict__ g2, const float* __restrict__ bb2,
                                          const float* __restrict__ ws,
                                          const unsigned short* __restrict__ pws,
                                          float* __restrict__ out)
{
    const int o  = blockIdx.x >> 5;
    const int r  = blockIdx.x & 31;
    const int bg = r & 1, tg = r >> 1;
    const int tid = threadIdx.x;

    __shared__ float red[4][2];
    __shared__ float sal, sbe;
    {
        float p1 = ws[BN2_OFF + tid*32 + o];
        float p2 = ws[BN2_OFF + tid*32 + 11 + o];
#pragma unroll
        for(int m=32;m>=1;m>>=1){ p1 += __shfl_xor(p1,m,64); p2 += __shfl_xor(p2,m,64); }
        const int wave = tid>>6, lane = tid&63;
        if(lane==0){ red[wave][0]=p1; red[wave][1]=p2; }
        __syncthreads();
        if(tid==0){
            float t1 = red[0][0]+red[1][0]+red[2][0]+red[3][0];
            float t2 = red[0][1]+red[1][1]+red[2][1]+red[3][1];
            const float inv = 1.0f/NELEM;
            float m = t1*inv;
            float v = t2*inv - m*m;
            float a = g2[o]*rsqrtf(v+EPS);
            sal = a; sbe = bb2[o] - m*a;
        }
        __syncthreads();
    }
    const float al = sal, be = sbe;

    const int b0 = bg*1024 + tid*4;
    const unsigned short* pp = pws + (size_t)o*TB + b0;
    float acc0=0.f, acc1=0.f, acc2=0.f, acc3=0.f;
#pragma unroll 8
    for(int i=0;i<64;i++){
        const int t = tg*64 + i;
        uint2 u = *(const uint2*)(pp + (size_t)t*NB);
        unsigned short a0 = (unsigned short)(u.x & 0xffff), a1 = (unsigned short)(u.x >> 16);
        unsigned short c0 = (unsigned short)(u.y & 0xffff), c1 = (unsigned short)(u.y >> 16);
        acc0 += leaky(fmaf(al, h2f(a0), be));
        acc1 += leaky(fmaf(al, h2f(a1), be));
        acc2 += leaky(fmaf(al, h2f(c0), be));
        acc3 += leaky(fmaf(al, h2f(c1), be));
    }
    atomicAdd(&out[(b0+0)*11+o], acc0*(1.0f/NT));
    atomicAdd(&out[(b0+1)*11+o], acc1*(1.0f/NT));
    atomicAdd(&out[(b0+2)*11+o], acc2*(1.0f/NT));
    atomicAdd(&out[(b0+3)*11+o], acc3*(1.0f/NT));
}

extern "C" void kernel_launch(void* const* d_in, const int* in_sizes, int n_in,
                              void* d_out, int out_size, void* d_ws, size_t ws_size,
                              hipStream_t stream)
{
    const float* x   = (const float*)d_in[0];
    const float* A   = (const float*)d_in[1];
    const float* g1  = (const float*)d_in[2];
    const float* bb1 = (const float*)d_in[3];
    const float* w1  = (const float*)d_in[4];
    const float* b1  = (const float*)d_in[5];
    const float* w2  = (const float*)d_in[6];
    const float* b2  = (const float*)d_in[7];
    const float* w3  = (const float*)d_in[8];
    const float* b3  = (const float*)d_in[9];
    const float* g2  = (const float*)d_in[10];
    const float* bb2 = (const float*)d_in[11];
    float* out = (float*)d_out;
    float* ws  = (float*)d_ws;
    unsigned short* xT  = (unsigned short*)((char*)d_ws + XT_BYTE);
    unsigned short* pws = (unsigned short*)((char*)d_ws + PWS_BYTE);

    (void)hipMemsetAsync(d_ws, 0, 40960, stream);                 // bn1/bn2 slots + par
    k0_tr  <<<2048, 256, 0, stream>>>(x, xT, ws);
    k2_fold<<<1,    256, 0, stream>>>(g1, bb1, w1, b1, w2, b2, w3, b3, A, ws, out);
    k34    <<<1024, 256, 0, stream>>>(xT, ws, pws);
    k6     <<<352,  256, 0, stream>>>(g2, bb2, ws, pws, out);
}